// Round 13
// baseline (4863.526 us; speedup 1.0000x reference)
//
#include <hip/hip_runtime.h>

typedef unsigned int uint32;
typedef unsigned short ushort16;
typedef __attribute__((ext_vector_type(8))) short short8;
typedef __attribute__((ext_vector_type(4))) float f32x4;

typedef __attribute__((address_space(1))) const unsigned char gbyte;
typedef __attribute__((address_space(3))) unsigned char lbyte;
#define GLDS16(g, l) __builtin_amdgcn_global_load_lds((gbyte*)(g), (lbyte*)(l), 16, 0, 0)

__device__ __forceinline__ float bf2f(ushort16 u) {
    return __uint_as_float(((uint32)u) << 16);
}
__device__ __forceinline__ float bflo(uint32 u) { return __uint_as_float(u << 16); }
__device__ __forceinline__ float bfhi(uint32 u) { return __uint_as_float(u & 0xffff0000u); }
__device__ __forceinline__ ushort16 f2bf(float f) {
    uint32 u = __float_as_uint(f);
    return (ushort16)((u + 0x7FFFu + ((u >> 16) & 1u)) >> 16);  // RNE
}
__device__ __forceinline__ float sigm(float x) {
    return __builtin_amdgcn_rcpf(1.f + __expf(-x));
}
__device__ __forceinline__ float tanh_f(float x) {
    return 1.f - 2.f * __builtin_amdgcn_rcpf(__expf(2.f * x) + 1.f);
}
// LICM-blocker only: dep on a loop-carried value available at STEP START (cst).
__device__ __forceinline__ int gated_zero_f(float dep) {
    int z; asm volatile("v_mov_b32 %0, 0" : "=v"(z) : "v"(dep)); return z;
}

// ---------------- f32 -> bf16 convert (vectorized x4, linear) ----------------
__global__ __launch_bounds__(256) void k_cvt_bf16(const float* __restrict__ in,
                                                  ushort16* __restrict__ out, int n4) {
    int i = blockIdx.x * 256 + threadIdx.x;
    int stride = gridDim.x * 256;
    for (; i < n4; i += stride) {
        float4 v = ((const float4*)in)[i];
        ushort4 o;
        o.x = f2bf(v.x); o.y = f2bf(v.y); o.z = f2bf(v.z); o.w = f2bf(v.w);
        ((ushort4*)out)[i] = o;
    }
}

// ---------------- features [b][t][768] f32 -> bf16 t-major [t*64+b][768] ----------------
__global__ __launch_bounds__(256) void k_cvt_tmaj(const float* __restrict__ in,
                                                  ushort16* __restrict__ out, int n4) {
    int i = blockIdx.x * 256 + threadIdx.x;
    int stride = gridDim.x * 256;
    for (; i < n4; i += stride) {
        float4 v = ((const float4*)in)[i];       // coalesced read
        int rem = i / 192;                        // 768/4 quads per row
        int q = i - rem * 192;
        int t = rem & 511, b = rem >> 9;
        ushort4 o;
        o.x = f2bf(v.x); o.y = f2bf(v.y); o.z = f2bf(v.z); o.w = f2bf(v.w);
        ((ushort4*)out)[(t * 64 + b) * 192 + q] = o;
    }
}

// ------- Whh [2][4H=1024][256] f32 -> MFMA B-fragment order bf16 -------
__global__ __launch_bounds__(256) void k_wfrag(const float* __restrict__ whh,
                                               ushort16* __restrict__ out) {
    int i = blockIdx.x * 256 + threadIdx.x;   // 0 .. 524287
    int j    = i & 7;
    int lane = (i >> 3) & 63;
    int kf   = (i >> 9) & 7;
    int nt   = (i >> 12) & 7;
    int w    = (i >> 15) & 7;
    int d    = (i >> 18) & 1;
    int g = nt >> 1, hh = nt & 1;
    int orow = g * 256 + w * 32 + hh * 16 + (lane & 15);
    int k = kf * 32 + (lane >> 4) * 8 + j;
    float v = whh[((size_t)d * 1024 + orow) * 256 + k];
    out[i] = f2bf(v);
}

// ---------------- bf16 MFMA GEMM into scan-friendly xg2 layout (r11, unchanged) ----------------
__global__ __launch_bounds__(256) void k_gemm_xg(const ushort16* __restrict__ A,
                                                 const ushort16* __restrict__ Bt,
                                                 const float* __restrict__ bias,
                                                 ushort16* __restrict__ C,
                                                 int M, int N, int K) {
    __shared__ ushort16 As[128 * 32];
    __shared__ ushort16 Bs[128 * 32];
    const int tid = threadIdx.x;
    const int bm = blockIdx.x * 128, bn = blockIdx.y * 128;
    const int lane = tid & 63, wave = tid >> 6;
    const int wr = (wave >> 1) * 64, wc = (wave & 1) * 64;
    const int l15 = lane & 15, l4 = lane >> 4;
    f32x4 acc[4][4] = {};
    const int ar = tid >> 2;
    const int ac = (tid & 3) * 8;
    const size_t rowA  = (size_t)(bm + ar) * K;
    const size_t rowA2 = (size_t)(bm + ar + 64) * K;
    const size_t rowB  = (size_t)(bn + ar) * K;
    const size_t rowB2 = (size_t)(bn + ar + 64) * K;

    for (int k0 = 0; k0 < K; k0 += 32) {
        GLDS16(&A[rowA + k0 + ac],  &As[tid * 8]);
        GLDS16(&A[rowA2 + k0 + ac], &As[2048 + tid * 8]);
        GLDS16(&Bt[rowB + k0 + ac],  &Bs[tid * 8]);
        GLDS16(&Bt[rowB2 + k0 + ac], &Bs[2048 + tid * 8]);
        __builtin_amdgcn_sched_barrier(0);
        asm volatile("s_waitcnt vmcnt(0)" ::: "memory");
        __syncthreads();

        short8 af[4], bfv[4];
#pragma unroll
        for (int i = 0; i < 4; i++) {
            af[i]  = *(const short8*)&As[(wr + i * 16 + l15) * 32 + l4 * 8];
            bfv[i] = *(const short8*)&Bs[(wc + i * 16 + l15) * 32 + l4 * 8];
        }
#pragma unroll
        for (int mi = 0; mi < 4; mi++)
#pragma unroll
            for (int ni = 0; ni < 4; ni++)
                acc[mi][ni] = __builtin_amdgcn_mfma_f32_16x16x32_bf16(af[mi], bfv[ni],
                                                                     acc[mi][ni], 0, 0, 0);
        __syncthreads();
    }

#pragma unroll
    for (int mi = 0; mi < 4; mi++) {
#pragma unroll
        for (int ni = 0; ni < 4; ni++) {
            int col = bn + wc + ni * 16 + l15;
            float bv = bias[col];
            int dcol = col >> 10, g = (col >> 8) & 3;
            int wvv = (col >> 5) & 7, hh = (col >> 4) & 1, l15c = col & 15;
            int nt = g * 2 + hh;
            int row0 = bm + wr + mi * 16 + l4 * 4;        // quad = rows row0..row0+3
            int batch0 = row0 & 63, tt = row0 >> 6;
            int b4 = batch0 & 15;
            int lanec = ((b4 >> 2) << 4) | l15c;
            size_t base = ((((size_t)((dcol << 2) | (batch0 >> 4)) * 512 + tt) * 8 + wvv) * 64
                           + lanec) * 32 + nt * 4;
            uint32 lo = (uint32)f2bf(acc[mi][ni][0] + bv) | ((uint32)f2bf(acc[mi][ni][1] + bv) << 16);
            uint32 hi = (uint32)f2bf(acc[mi][ni][2] + bv) | ((uint32)f2bf(acc[mi][ni][3] + bv) << 16);
            *(uint2*)&C[base] = make_uint2(lo, hi);       // 8B store
        }
    }
}

// ---------------- MFMA LSTM scan: r11 phase schedule VERBATIM, x2 manual unroll ----------------
// r8/r9/r12 showed the phase schedule is fragile: ONLY r10/r11's exact interleave
// passes. This kernel duplicates r11's step body with hardcoded buffers (hf0/hf1)
// — no reordering, no new dataflow classes; removes cur-indexing + xc<->xn copies.
#define SCAN_STEP(HCUR, HNXT)                                                            \
    {                                                                                    \
        xp += dstep;                                                                     \
        f32x4 acc[8];                                                                    \
        acc[0][0]=bflo(xc0.x); acc[0][1]=bfhi(xc0.x); acc[0][2]=bflo(xc0.y); acc[0][3]=bfhi(xc0.y); \
        acc[1][0]=bflo(xc0.z); acc[1][1]=bfhi(xc0.z); acc[1][2]=bflo(xc0.w); acc[1][3]=bfhi(xc0.w); \
        acc[2][0]=bflo(xc1.x); acc[2][1]=bfhi(xc1.x); acc[2][2]=bflo(xc1.y); acc[2][3]=bfhi(xc1.y); \
        acc[3][0]=bflo(xc1.z); acc[3][1]=bfhi(xc1.z); acc[3][2]=bflo(xc1.w); acc[3][3]=bfhi(xc1.w); \
        acc[4][0]=bflo(xc2.x); acc[4][1]=bfhi(xc2.x); acc[4][2]=bflo(xc2.y); acc[4][3]=bfhi(xc2.y); \
        acc[5][0]=bflo(xc2.z); acc[5][1]=bfhi(xc2.z); acc[5][2]=bflo(xc2.w); acc[5][3]=bfhi(xc2.w); \
        acc[6][0]=bflo(xc3.x); acc[6][1]=bfhi(xc3.x); acc[6][2]=bflo(xc3.y); acc[6][3]=bfhi(xc3.y); \
        acc[7][0]=bflo(xc3.z); acc[7][1]=bfhi(xc3.z); acc[7][2]=bflo(xc3.w); acc[7][3]=bfhi(xc3.w); \
        const ushort16* hcur = (HCUR);                                                   \
        {   /* kf4 (LDS) — builtin first */                                              \
            short8 a4 = *(const short8*)&hcur[4 * 512 + swl];                            \
            _Pragma("unroll")                                                            \
            for (int nt = 0; nt < 8; ++nt) {                                             \
                short8 b = *(const short8*)&wl[((wv * 8 + nt) * 2 + 0) * 512 + lane * 8];\
                acc[nt] = __builtin_amdgcn_mfma_f32_16x16x32_bf16(a4, b, acc[nt], 0, 0, 0); \
            }                                                                            \
        }                                                                                \
        short8 a0 = *(const short8*)&hcur[0 * 512 + swl];                                \
        int z0 = gated_zero_f(cst[0]);                                                   \
        short8 w6a[4];                                                                   \
        _Pragma("unroll")                                                                \
        for (int nt = 0; nt < 4; ++nt) w6a[nt] = *(const short8*)&w6[nt * 4096 + z0];    \
        _Pragma("unroll")                                                                \
        for (int nt = 0; nt < 8; ++nt)                                                   \
            asm volatile("v_mfma_f32_16x16x32_bf16 %0, %1, %2, %0"                       \
                         : "+v"(acc[nt]) : "v"(a0), "a"(wa[nt][0]));                     \
        short8 a1 = *(const short8*)&hcur[1 * 512 + swl];                                \
        int z1 = gated_zero_f(cst[0]);                                                   \
        short8 w6b[4];                                                                   \
        _Pragma("unroll")                                                                \
        for (int nt = 0; nt < 4; ++nt) w6b[nt] = *(const short8*)&w6[(nt + 4) * 4096 + z1]; \
        _Pragma("unroll")                                                                \
        for (int nt = 0; nt < 8; ++nt)                                                   \
            asm volatile("v_mfma_f32_16x16x32_bf16 %0, %1, %2, %0"                       \
                         : "+v"(acc[nt]) : "v"(a1), "a"(wa[nt][1]));                     \
        short8 a2 = *(const short8*)&hcur[2 * 512 + swl];                                \
        int z2 = gated_zero_f(cst[0]);                                                   \
        short8 w7a[4];                                                                   \
        _Pragma("unroll")                                                                \
        for (int nt = 0; nt < 4; ++nt) w7a[nt] = *(const short8*)&w6[nt * 4096 + 512 + z2]; \
        _Pragma("unroll")                                                                \
        for (int nt = 0; nt < 8; ++nt)                                                   \
            asm volatile("v_mfma_f32_16x16x32_bf16 %0, %1, %2, %0"                       \
                         : "+v"(acc[nt]) : "v"(a2), "a"(wa[nt][2]));                     \
        short8 a6 = *(const short8*)&hcur[6 * 512 + swl];                                \
        _Pragma("unroll")                                                                \
        for (int nt = 0; nt < 4; ++nt)                                                   \
            acc[nt] = __builtin_amdgcn_mfma_f32_16x16x32_bf16(a6, w6a[nt], acc[nt], 0, 0, 0); \
        short8 a3 = *(const short8*)&hcur[3 * 512 + swl];                                \
        int z3 = gated_zero_f(cst[0]);                                                   \
        short8 w7b[4];                                                                   \
        _Pragma("unroll")                                                                \
        for (int nt = 0; nt < 4; ++nt) w7b[nt] = *(const short8*)&w6[(nt + 4) * 4096 + 512 + z3]; \
        _Pragma("unroll")                                                                \
        for (int nt = 0; nt < 8; ++nt)                                                   \
            asm volatile("v_mfma_f32_16x16x32_bf16 %0, %1, %2, %0"                       \
                         : "+v"(acc[nt]) : "v"(a3), "a"(wa[nt][3]));                     \
        uint4 xn0 = ((const uint4*)xp)[0];                                               \
        uint4 xn1 = ((const uint4*)xp)[1];                                               \
        uint4 xn2 = ((const uint4*)xp)[2];                                               \
        uint4 xn3 = ((const uint4*)xp)[3];                                               \
        _Pragma("unroll")                                                                \
        for (int nt = 4; nt < 8; ++nt)                                                   \
            acc[nt] = __builtin_amdgcn_mfma_f32_16x16x32_bf16(a6, w6b[nt - 4], acc[nt], 0, 0, 0); \
        {   /* kf5 (LDS, builtin) */                                                     \
            short8 a5 = *(const short8*)&hcur[5 * 512 + swl];                            \
            _Pragma("unroll")                                                            \
            for (int nt = 0; nt < 8; ++nt) {                                             \
                short8 b = *(const short8*)&wl[((wv * 8 + nt) * 2 + 1) * 512 + lane * 8];\
                acc[nt] = __builtin_amdgcn_mfma_f32_16x16x32_bf16(a5, b, acc[nt], 0, 0, 0); \
            }                                                                            \
        }                                                                                \
        short8 a7 = *(const short8*)&hcur[7 * 512 + swl];                                \
        _Pragma("unroll")                                                                \
        for (int nt = 0; nt < 4; ++nt)                                                   \
            acc[nt] = __builtin_amdgcn_mfma_f32_16x16x32_bf16(a7, w7a[nt], acc[nt], 0, 0, 0); \
        _Pragma("unroll")                                                                \
        for (int nt = 4; nt < 8; ++nt)                                                   \
            acc[nt] = __builtin_amdgcn_mfma_f32_16x16x32_bf16(a7, w7b[nt - 4], acc[nt], 0, 0, 0); \
        float hv[8];                                                                     \
        _Pragma("unroll")                                                                \
        for (int hh = 0; hh < 2; ++hh)                                                   \
            _Pragma("unroll")                                                            \
            for (int r = 0; r < 4; ++r) {                                                \
                float ig = sigm(acc[0 + hh][r]);                                         \
                float fg = sigm(acc[2 + hh][r]);                                         \
                float gg = tanh_f(acc[4 + hh][r]);                                       \
                float og = sigm(acc[6 + hh][r]);                                         \
                float c = fg * cst[hh * 4 + r] + ig * gg;                                \
                cst[hh * 4 + r] = c;                                                     \
                hv[hh * 4 + r] = og * tanh_f(c);                                         \
            }                                                                            \
        uint32 p01, p23, p45, p67;                                                       \
        asm volatile("v_cvt_pk_bf16_f32 %0, %1, %2" : "=v"(p01) : "v"(hv[0]), "v"(hv[1])); \
        asm volatile("v_cvt_pk_bf16_f32 %0, %1, %2" : "=v"(p23) : "v"(hv[2]), "v"(hv[3])); \
        asm volatile("v_cvt_pk_bf16_f32 %0, %1, %2" : "=v"(p45) : "v"(hv[4]), "v"(hv[5])); \
        asm volatile("v_cvt_pk_bf16_f32 %0, %1, %2" : "=v"(p67) : "v"(hv[6]), "v"(hv[7])); \
        ushort16 hb[8];                                                                  \
        hb[0] = (ushort16)p01; hb[1] = (ushort16)(p01 >> 16);                            \
        hb[2] = (ushort16)p23; hb[3] = (ushort16)(p23 >> 16);                            \
        hb[4] = (ushort16)p45; hb[5] = (ushort16)(p45 >> 16);                            \
        hb[6] = (ushort16)p67; hb[7] = (ushort16)(p67 >> 16);                            \
        ushort16* hnxt = (HNXT);                                                         \
        _Pragma("unroll")                                                                \
        for (int hh = 0; hh < 2; ++hh)                                                   \
            _Pragma("unroll")                                                            \
            for (int r = 0; r < 4; ++r) {                                                \
                hnxt[dsa[hh * 4 + r]] = hb[hh * 4 + r];                                  \
                hp[r * 512 + hh * 16] = hb[hh * 4 + r];                                  \
            }                                                                            \
        hp += hstep;                                                                     \
        __builtin_amdgcn_sched_barrier(0);                                               \
        asm volatile("s_waitcnt lgkmcnt(0)" ::: "memory");                               \
        __builtin_amdgcn_s_barrier();                                                    \
        __builtin_amdgcn_sched_barrier(0);                                               \
        xc0 = xn0; xc1 = xn1; xc2 = xn2; xc3 = xn3;                                      \
    }

__global__ __launch_bounds__(512, 2) void k_lstm_scan9(const ushort16* __restrict__ xg2,
                                                       const ushort16* __restrict__ w2,
                                                       ushort16* __restrict__ hout) {
    extern __shared__ char smem[];
    ushort16* hf = (ushort16*)smem;                 // 2 x 4096 bf16 (16KB)
    ushort16* wl = (ushort16*)(smem + 16384);       // kf4,5: 128KB

    const int bg = blockIdx.x >> 1, d = blockIdx.x & 1;
    const int tid = threadIdx.x;
    const int wv = tid >> 6, lane = tid & 63;
    const int l15 = lane & 15, l4 = lane >> 4;
    const int swl = (lane ^ (lane >> 3)) * 8;       // consumer A-frag chunk swizzle
    const size_t dbase = (size_t)d * 262144;

    // zero h buffers (h_0 = 0)
    for (int q = tid; q < 1024; q += 512) ((uint4*)hf)[q] = make_uint4(0, 0, 0, 0);
    // LDS weights kf4,5
    {
        const uint4* src = (const uint4*)(w2 + dbase);
        uint4* dst = (uint4*)wl;
        for (int q = tid; q < 8192; q += 512) {
            int sidx = q >> 7;           // wv*8+nt
            int kp = (q >> 6) & 1;       // kf-4
            int off = q & 63;
            dst[q] = src[(sidx * 8 + 4 + kp) * 64 + off];
        }
    }
    // AGPR weights kf0..3
    const ushort16* wbase = w2 + dbase + (size_t)wv * 32768 + lane * 8;
    short8 wa[8][4];
#pragma unroll
    for (int nt = 0; nt < 8; ++nt)
#pragma unroll
        for (int kf = 0; kf < 4; ++kf)
            wa[nt][kf] = *(const short8*)&wbase[nt * 4096 + kf * 512];
    const ushort16* w6 = wbase + 6 * 512;   // kf6 base; kf7 = +512
    __syncthreads();

    const int t0 = d ? 511 : 0;
    const int dstep = d ? -16384 : 16384;
    const int hstep = d ? -32768 : 32768;
    const ushort16* xp = xg2 + ((((size_t)(d * 4 + bg) * 512 + t0) * 8 + wv) * 64 + lane) * 32;
    ushort16* hp = hout + ((size_t)t0 * 32768 + (bg * 16 + l4 * 4) * 512 + d * 256 + wv * 32 + l15);

    int dsa[8];
#pragma unroll
    for (int hh = 0; hh < 2; ++hh)
#pragma unroll
        for (int r = 0; r < 4; ++r) {
            int lp = (hh * 2 + (l15 >> 3)) * 16 + l4 * 4 + r;
            int ch = lp ^ (lp >> 3);
            dsa[hh * 4 + r] = wv * 512 + ch * 8 + (l15 & 7);
        }

    uint4 xc0 = ((const uint4*)xp)[0];
    uint4 xc1 = ((const uint4*)xp)[1];
    uint4 xc2 = ((const uint4*)xp)[2];
    uint4 xc3 = ((const uint4*)xp)[3];
    float cst[8] = {0.f, 0.f, 0.f, 0.f, 0.f, 0.f, 0.f, 0.f};
    ushort16* hf0 = hf;
    ushort16* hf1 = hf + 4096;

    for (int s = 0; s < 256; ++s) {
        SCAN_STEP(hf0, hf1)
        SCAN_STEP(hf1, hf0)
    }
}

// ---------------- logits = h1[t*64+b][512](bf16) @ clsW[9,512]^T + clsb -> f32 [b][t][9] ----------------
// k-loop vectorized: short8 h-reads + float4 w-reads (3 b128 LDS reads / 8 k).
__global__ __launch_bounds__(256) void k_logits(const ushort16* __restrict__ h1,
                                                const float* __restrict__ Wc,
                                                const float* __restrict__ bc,
                                                float* __restrict__ out) {
    __shared__ ushort16 hs[16 * 512];
    __shared__ float wsm[9 * 512];
    __shared__ float bs[9];
    const int tid = threadIdx.x;
    const size_t row0 = (size_t)blockIdx.x * 16;
    const uint4* src = (const uint4*)(h1 + row0 * 512);
    uint4* dst = (uint4*)hs;
#pragma unroll
    for (int i = 0; i < 4; i++) dst[tid + i * 256] = src[tid + i * 256];
    for (int i = tid; i < 4608; i += 256) wsm[i] = Wc[i];
    if (tid < 9) bs[tid] = bc[tid];
    __syncthreads();
    if (tid < 144) {
        int r = tid / 9, l = tid - r * 9;
        float acc = bs[l];
        const ushort16* hr = &hs[r * 512];
        const float4* w4 = (const float4*)&wsm[l * 512];
        for (int k8 = 0; k8 < 64; k8++) {
            short8 h8 = *(const short8*)&hr[k8 * 8];
            float4 wa_ = w4[k8 * 2];
            float4 wb_ = w4[k8 * 2 + 1];
            acc += bf2f((ushort16)h8[0]) * wa_.x;
            acc += bf2f((ushort16)h8[1]) * wa_.y;
            acc += bf2f((ushort16)h8[2]) * wa_.z;
            acc += bf2f((ushort16)h8[3]) * wa_.w;
            acc += bf2f((ushort16)h8[4]) * wb_.x;
            acc += bf2f((ushort16)h8[5]) * wb_.y;
            acc += bf2f((ushort16)h8[6]) * wb_.z;
            acc += bf2f((ushort16)h8[7]) * wb_.w;
        }
        int rowidx = (int)row0 + r;             // t-major: row = t*64 + b
        int bb = rowidx & 63, tt = rowidx >> 6;
        out[((size_t)bb * 512 + tt) * 9 + l] = acc;
    }
}

// ---------------- CRF NLL per batch (timesteps [1, 511)) ----------------
__global__ __launch_bounds__(64) void k_crf(const float* __restrict__ logits,
                                            const int* __restrict__ labels,
                                            const float* __restrict__ start,
                                            const float* __restrict__ endv,
                                            const float* __restrict__ trans,
                                            float* __restrict__ perb) {
    const int b = blockIdx.x, lane = threadIdx.x;
    __shared__ float tr[81];
    __shared__ float emb[510 * 9];
    for (int i = lane; i < 81; i += 64) tr[i] = trans[i];
    const float* em = logits + (size_t)b * 512 * 9;
    for (int i = lane; i < 4590; i += 64) emb[i] = em[9 + i];
    __syncthreads();
    const int* lb = labels + (size_t)b * 512;

    float acc = 0.f;
    for (int s = lane; s < 510; s += 64) acc += emb[s * 9 + lb[s + 1]];
    for (int s = lane; s < 509; s += 64) acc += tr[lb[s + 1] * 9 + lb[s + 2]];
#pragma unroll
    for (int off = 32; off; off >>= 1) acc += __shfl_down(acc, off);

    const int j = (lane < 9) ? lane : 0;
    float alpha = start[j] + emb[j];
    for (int s = 1; s < 510; ++s) {
        float v[9];
        float m = -3.4e38f;
#pragma unroll
        for (int i = 0; i < 9; i++) {
            float ai = __shfl(alpha, i);
            float t = ai + tr[i * 9 + j];
            v[i] = t;
            m = fmaxf(m, t);
        }
        float sum = 0.f;
#pragma unroll
        for (int i = 0; i < 9; i++) sum += __expf(v[i] - m);
        alpha = m + __logf(sum) + emb[s * 9 + j];
    }
    float ae = alpha + endv[j];
    float mm = -3.4e38f;
#pragma unroll
    for (int i = 0; i < 9; i++) mm = fmaxf(mm, __shfl(ae, i));
    float ss = 0.f;
#pragma unroll
    for (int i = 0; i < 9; i++) ss += __expf(__shfl(ae, i) - mm);
    float logZ = mm + __logf(ss);
    if (lane == 0) {
        float num = acc + start[lb[1]] + endv[lb[510]];
        perb[b] = logZ - num;
    }
}

__global__ __launch_bounds__(64) void k_reduce(const float* __restrict__ perb,
                                               float* __restrict__ out) {
    float v = perb[threadIdx.x];
#pragma unroll
    for (int off = 32; off; off >>= 1) v += __shfl_down(v, off);
    if (threadIdx.x == 0) out[0] = v * (1.f / 64.f);
}

extern "C" void kernel_launch(void* const* d_in, const int* in_sizes, int n_in,
                              void* d_out, int out_size, void* d_ws, size_t ws_size,
                              hipStream_t stream) {
    const float* features = (const float*)d_in[0];
    const int*   labels   = (const int*)d_in[1];
    const float* w0ih = (const float*)d_in[3];
    const float* w0hh = (const float*)d_in[4];
    const float* b0   = (const float*)d_in[5];
    const float* w1ih = (const float*)d_in[6];
    const float* w1hh = (const float*)d_in[7];
    const float* b1   = (const float*)d_in[8];
    const float* clsW = (const float*)d_in[9];
    const float* clsb = (const float*)d_in[10];
    const float* cstart = (const float*)d_in[11];
    const float* cend   = (const float*)d_in[12];
    const float* ctrans = (const float*)d_in[13];

    char* ws = (char*)d_ws;
    ushort16* featbf = (ushort16*)(ws + 0);              // t-major [t*64+b][768]
    ushort16* h1buf  = (ushort16*)(ws + 0);              // reuses feat region after GEMM0
    ushort16* xg2    = (ushort16*)(ws + 50331648);       // 134217728 B
    ushort16* h0     = (ushort16*)(ws + 184549376);      // 33554432 B (t-major)
    ushort16* wih0   = (ushort16*)(ws + 218103808);
    ushort16* wih1   = (ushort16*)(ws + 221249536);
    ushort16* w2_0   = (ushort16*)(ws + 223346688);
    ushort16* w2_1   = (ushort16*)(ws + 224395264);
    float*    perb   = (float*)(ws + 225443840);

    float* outF = (float*)d_out;
    float* logitsF = outF + 1;

    k_cvt_tmaj<<<dim3(2048), dim3(256), 0, stream>>>(features, featbf, 25165824 / 4);
    k_cvt_bf16<<<dim3(512), dim3(256), 0, stream>>>(w0ih, wih0, 1572864 / 4);
    k_cvt_bf16<<<dim3(512), dim3(256), 0, stream>>>(w1ih, wih1, 1048576 / 4);
    k_wfrag<<<dim3(2048), dim3(256), 0, stream>>>(w0hh, w2_0);
    k_wfrag<<<dim3(2048), dim3(256), 0, stream>>>(w1hh, w2_1);

    // layer 0 (A rows t-major for both GEMMs)
    k_gemm_xg<<<dim3(256, 16), dim3(256), 0, stream>>>(featbf, wih0, b0, xg2, 32768, 2048, 768);
    k_lstm_scan9<<<dim3(8), dim3(512), 147456, stream>>>(xg2, w2_0, h0);
    // layer 1
    k_gemm_xg<<<dim3(256, 16), dim3(256), 0, stream>>>(h0, wih1, b1, xg2, 32768, 2048, 512);
    k_lstm_scan9<<<dim3(8), dim3(512), 147456, stream>>>(xg2, w2_1, h1buf);
    // classifier + CRF
    k_logits<<<dim3(2048), dim3(256), 0, stream>>>(h1buf, clsW, clsb, logitsF);
    k_crf<<<dim3(64), dim3(64), 0, stream>>>(logitsF, labels, cstart, cend, ctrans, perb);
    k_reduce<<<dim3(1), dim3(64), 0, stream>>>(perb, outF);
}

// Round 14
// 4359.930 us; speedup vs baseline: 1.1155x; 1.1155x over previous
//
#include <hip/hip_runtime.h>

typedef unsigned int uint32;
typedef unsigned short ushort16;
typedef __attribute__((ext_vector_type(8))) short short8;
typedef __attribute__((ext_vector_type(4))) float f32x4;

typedef __attribute__((address_space(1))) const unsigned char gbyte;
typedef __attribute__((address_space(3))) unsigned char lbyte;
#define GLDS16(g, l) __builtin_amdgcn_global_load_lds((gbyte*)(g), (lbyte*)(l), 16, 0, 0)

__device__ __forceinline__ float bf2f(ushort16 u) {
    return __uint_as_float(((uint32)u) << 16);
}
__device__ __forceinline__ float bflo(uint32 u) { return __uint_as_float(u << 16); }
__device__ __forceinline__ float bfhi(uint32 u) { return __uint_as_float(u & 0xffff0000u); }
__device__ __forceinline__ ushort16 f2bf(float f) {
    uint32 u = __float_as_uint(f);
    return (ushort16)((u + 0x7FFFu + ((u >> 16) & 1u)) >> 16);  // RNE
}
__device__ __forceinline__ float sigm(float x) {
    return __builtin_amdgcn_rcpf(1.f + __expf(-x));
}
__device__ __forceinline__ float tanh_f(float x) {
    return 1.f - 2.f * __builtin_amdgcn_rcpf(__expf(2.f * x) + 1.f);
}
// LICM-blocker only: dep on a loop-carried value available at STEP START (cst).
__device__ __forceinline__ int gated_zero_f(float dep) {
    int z; asm volatile("v_mov_b32 %0, 0" : "=v"(z) : "v"(dep)); return z;
}

// ---------------- f32 -> bf16 convert (vectorized x4, linear) ----------------
__global__ __launch_bounds__(256) void k_cvt_bf16(const float* __restrict__ in,
                                                  ushort16* __restrict__ out, int n4) {
    int i = blockIdx.x * 256 + threadIdx.x;
    int stride = gridDim.x * 256;
    for (; i < n4; i += stride) {
        float4 v = ((const float4*)in)[i];
        ushort4 o;
        o.x = f2bf(v.x); o.y = f2bf(v.y); o.z = f2bf(v.z); o.w = f2bf(v.w);
        ((ushort4*)out)[i] = o;
    }
}

// ---------------- features [b][t][768] f32 -> bf16 t-major [t*64+b][768] ----------------
__global__ __launch_bounds__(256) void k_cvt_tmaj(const float* __restrict__ in,
                                                  ushort16* __restrict__ out, int n4) {
    int i = blockIdx.x * 256 + threadIdx.x;
    int stride = gridDim.x * 256;
    for (; i < n4; i += stride) {
        float4 v = ((const float4*)in)[i];       // coalesced read
        int rem = i / 192;                        // 768/4 quads per row
        int q = i - rem * 192;
        int t = rem & 511, b = rem >> 9;
        ushort4 o;
        o.x = f2bf(v.x); o.y = f2bf(v.y); o.z = f2bf(v.z); o.w = f2bf(v.w);
        ((ushort4*)out)[(t * 64 + b) * 192 + q] = o;
    }
}

// ------- Whh [2][4H=1024][256] f32 -> MFMA B-fragment order bf16 -------
__global__ __launch_bounds__(256) void k_wfrag(const float* __restrict__ whh,
                                               ushort16* __restrict__ out) {
    int i = blockIdx.x * 256 + threadIdx.x;   // 0 .. 524287
    int j    = i & 7;
    int lane = (i >> 3) & 63;
    int kf   = (i >> 9) & 7;
    int nt   = (i >> 12) & 7;
    int w    = (i >> 15) & 7;
    int d    = (i >> 18) & 1;
    int g = nt >> 1, hh = nt & 1;
    int orow = g * 256 + w * 32 + hh * 16 + (lane & 15);
    int k = kf * 32 + (lane >> 4) * 8 + j;
    float v = whh[((size_t)d * 1024 + orow) * 256 + k];
    out[i] = f2bf(v);
}

// ---------------- bf16 MFMA GEMM into scan-friendly xg2 layout (r11, unchanged) ----------------
__global__ __launch_bounds__(256) void k_gemm_xg(const ushort16* __restrict__ A,
                                                 const ushort16* __restrict__ Bt,
                                                 const float* __restrict__ bias,
                                                 ushort16* __restrict__ C,
                                                 int M, int N, int K) {
    __shared__ ushort16 As[128 * 32];
    __shared__ ushort16 Bs[128 * 32];
    const int tid = threadIdx.x;
    const int bm = blockIdx.x * 128, bn = blockIdx.y * 128;
    const int lane = tid & 63, wave = tid >> 6;
    const int wr = (wave >> 1) * 64, wc = (wave & 1) * 64;
    const int l15 = lane & 15, l4 = lane >> 4;
    f32x4 acc[4][4] = {};
    const int ar = tid >> 2;
    const int ac = (tid & 3) * 8;
    const size_t rowA  = (size_t)(bm + ar) * K;
    const size_t rowA2 = (size_t)(bm + ar + 64) * K;
    const size_t rowB  = (size_t)(bn + ar) * K;
    const size_t rowB2 = (size_t)(bn + ar + 64) * K;

    for (int k0 = 0; k0 < K; k0 += 32) {
        GLDS16(&A[rowA + k0 + ac],  &As[tid * 8]);
        GLDS16(&A[rowA2 + k0 + ac], &As[2048 + tid * 8]);
        GLDS16(&Bt[rowB + k0 + ac],  &Bs[tid * 8]);
        GLDS16(&Bt[rowB2 + k0 + ac], &Bs[2048 + tid * 8]);
        __builtin_amdgcn_sched_barrier(0);
        asm volatile("s_waitcnt vmcnt(0)" ::: "memory");
        __syncthreads();

        short8 af[4], bfv[4];
#pragma unroll
        for (int i = 0; i < 4; i++) {
            af[i]  = *(const short8*)&As[(wr + i * 16 + l15) * 32 + l4 * 8];
            bfv[i] = *(const short8*)&Bs[(wc + i * 16 + l15) * 32 + l4 * 8];
        }
#pragma unroll
        for (int mi = 0; mi < 4; mi++)
#pragma unroll
            for (int ni = 0; ni < 4; ni++)
                acc[mi][ni] = __builtin_amdgcn_mfma_f32_16x16x32_bf16(af[mi], bfv[ni],
                                                                     acc[mi][ni], 0, 0, 0);
        __syncthreads();
    }

#pragma unroll
    for (int mi = 0; mi < 4; mi++) {
#pragma unroll
        for (int ni = 0; ni < 4; ni++) {
            int col = bn + wc + ni * 16 + l15;
            float bv = bias[col];
            int dcol = col >> 10, g = (col >> 8) & 3;
            int wvv = (col >> 5) & 7, hh = (col >> 4) & 1, l15c = col & 15;
            int nt = g * 2 + hh;
            int row0 = bm + wr + mi * 16 + l4 * 4;        // quad = rows row0..row0+3
            int batch0 = row0 & 63, tt = row0 >> 6;
            int b4 = batch0 & 15;
            int lanec = ((b4 >> 2) << 4) | l15c;
            size_t base = ((((size_t)((dcol << 2) | (batch0 >> 4)) * 512 + tt) * 8 + wvv) * 64
                           + lanec) * 32 + nt * 4;
            uint32 lo = (uint32)f2bf(acc[mi][ni][0] + bv) | ((uint32)f2bf(acc[mi][ni][1] + bv) << 16);
            uint32 hi = (uint32)f2bf(acc[mi][ni][2] + bv) | ((uint32)f2bf(acc[mi][ni][3] + bv) << 16);
            *(uint2*)&C[base] = make_uint2(lo, hi);       // 8B store
        }
    }
}

// ---------------- MFMA LSTM scan: r11 schedule FROZEN; 16 blocks (mb=8) ----------------
// 16 blocks = 8 batch-groups(8) x 2 dirs -> 2x CUs active. MFMA rows 8-15 are
// don't-care (garbage confined to garbage A-rows; saturating activations keep
// them finite). xg2 layout UNCHANGED: block bg reads lane slice (bg&1)*32..+31
// of chunk d*4+(bg>>1) (wrapped addressing for don't-care lanes stays within
// GEMM-written data). hout stores guarded l4<2 (16 blocks x 8 batches = 64).
// Step body is r11 verbatim — r8/r9/r12 proved the phase schedule is fragile.
__global__ __launch_bounds__(512, 2) void k_lstm_scan5(const ushort16* __restrict__ xg2,
                                                       const ushort16* __restrict__ w2,
                                                       ushort16* __restrict__ hout) {
    extern __shared__ char smem[];
    ushort16* hf = (ushort16*)smem;                 // 2 x 4096 bf16 (16KB)
    ushort16* wl = (ushort16*)(smem + 16384);       // kf4,5: 128KB

    const int bg = blockIdx.x >> 1, d = blockIdx.x & 1;   // bg 0..7
    const int tid = threadIdx.x;
    const int wv = tid >> 6, lane = tid & 63;
    const int l15 = lane & 15, l4 = lane >> 4;
    const int swl = (lane ^ (lane >> 3)) * 8;       // consumer A-frag chunk swizzle
    const size_t dbase = (size_t)d * 262144;
    const int glane = (((bg & 1) * 32) + lane) & 63;    // xg2 lane slot (wrapped for don't-care)

    // zero h buffers (h_0 = 0)
    for (int q = tid; q < 1024; q += 512) ((uint4*)hf)[q] = make_uint4(0, 0, 0, 0);
    // LDS weights kf4,5: wl[((wv*8+nt)*2 + kp)*512 + lane*8], 8192 uint4 = 128KB
    {
        const uint4* src = (const uint4*)(w2 + dbase);
        uint4* dst = (uint4*)wl;
        for (int q = tid; q < 8192; q += 512) {
            int sidx = q >> 7;           // wv*8+nt
            int kp = (q >> 6) & 1;       // kf-4
            int off = q & 63;
            dst[q] = src[(sidx * 8 + 4 + kp) * 64 + off];
        }
    }
    // AGPR weights kf0..3 (only ever used via "a" constraints -> stay in AGPRs)
    const ushort16* wbase = w2 + dbase + (size_t)wv * 32768 + lane * 8;
    short8 wa[8][4];
#pragma unroll
    for (int nt = 0; nt < 8; ++nt)
#pragma unroll
        for (int kf = 0; kf < 4; ++kf)
            wa[nt][kf] = *(const short8*)&wbase[nt * 4096 + kf * 512];
    const ushort16* w6 = wbase + 6 * 512;   // kf6 base; kf7 = +512
    __syncthreads();

    const int t0 = d ? 511 : 0;
    const int dstep = d ? -16384 : 16384;
    const int hstep = d ? -32768 : 32768;
    const ushort16* xp = xg2 + ((((size_t)(d * 4 + (bg >> 1)) * 512 + t0) * 8 + wv) * 64 + glane) * 32;
    ushort16* hp = hout + ((size_t)t0 * 32768 + (bg * 8 + l4 * 4) * 512 + d * 256 + wv * 32 + l15);
    const bool valid = (l4 < 2);                        // batches bg*8 + l4*4 + r, l4<2 only

    // precomputed ds_write addresses (step-invariant)
    int dsa[8];
#pragma unroll
    for (int hh = 0; hh < 2; ++hh)
#pragma unroll
        for (int r = 0; r < 4; ++r) {
            int lp = (hh * 2 + (l15 >> 3)) * 16 + l4 * 4 + r;
            int ch = lp ^ (lp >> 3);
            dsa[hh * 4 + r] = wv * 512 + ch * 8 + (l15 & 7);
        }

    uint4 xc0 = ((const uint4*)xp)[0];
    uint4 xc1 = ((const uint4*)xp)[1];
    uint4 xc2 = ((const uint4*)xp)[2];
    uint4 xc3 = ((const uint4*)xp)[3];
    float cst[8] = {0.f, 0.f, 0.f, 0.f, 0.f, 0.f, 0.f, 0.f};
    int cur = 0;

    for (int s = 0; s < 512; ++s) {
        xp += dstep;

        // issue ALL stream loads up front? NO — r11 staggered order kept verbatim.
        // gate pre-activations init = x (MFMA C-init)
        f32x4 acc[8];
        acc[0][0]=bflo(xc0.x); acc[0][1]=bfhi(xc0.x); acc[0][2]=bflo(xc0.y); acc[0][3]=bfhi(xc0.y);
        acc[1][0]=bflo(xc0.z); acc[1][1]=bfhi(xc0.z); acc[1][2]=bflo(xc0.w); acc[1][3]=bfhi(xc0.w);
        acc[2][0]=bflo(xc1.x); acc[2][1]=bfhi(xc1.x); acc[2][2]=bflo(xc1.y); acc[2][3]=bfhi(xc1.y);
        acc[3][0]=bflo(xc1.z); acc[3][1]=bfhi(xc1.z); acc[3][2]=bflo(xc1.w); acc[3][3]=bfhi(xc1.w);
        acc[4][0]=bflo(xc2.x); acc[4][1]=bfhi(xc2.x); acc[4][2]=bflo(xc2.y); acc[4][3]=bfhi(xc2.y);
        acc[5][0]=bflo(xc2.z); acc[5][1]=bfhi(xc2.z); acc[5][2]=bflo(xc2.w); acc[5][3]=bfhi(xc2.w);
        acc[6][0]=bflo(xc3.x); acc[6][1]=bfhi(xc3.x); acc[6][2]=bflo(xc3.y); acc[6][3]=bfhi(xc3.y);
        acc[7][0]=bflo(xc3.z); acc[7][1]=bfhi(xc3.z); acc[7][2]=bflo(xc3.w); acc[7][3]=bfhi(xc3.w);

        const ushort16* hcur = hf + cur * 4096;

        // kf4 (LDS) — builtin first
        {
            short8 a4 = *(const short8*)&hcur[4 * 512 + swl];
#pragma unroll
            for (int nt = 0; nt < 8; ++nt) {
                short8 b = *(const short8*)&wl[((wv * 8 + nt) * 2 + 0) * 512 + lane * 8];
                acc[nt] = __builtin_amdgcn_mfma_f32_16x16x32_bf16(a4, b, acc[nt], 0, 0, 0);
            }
        }
        // kf0 (AGPR) + issue stream w6a
        short8 a0 = *(const short8*)&hcur[0 * 512 + swl];
        int z0 = gated_zero_f(cst[0]);
        short8 w6a[4];
#pragma unroll
        for (int nt = 0; nt < 4; ++nt) w6a[nt] = *(const short8*)&w6[nt * 4096 + z0];
#pragma unroll
        for (int nt = 0; nt < 8; ++nt)
            asm volatile("v_mfma_f32_16x16x32_bf16 %0, %1, %2, %0"
                         : "+v"(acc[nt]) : "v"(a0), "a"(wa[nt][0]));
        // kf1 + issue w6b
        short8 a1 = *(const short8*)&hcur[1 * 512 + swl];
        int z1 = gated_zero_f(cst[0]);
        short8 w6b[4];
#pragma unroll
        for (int nt = 0; nt < 4; ++nt) w6b[nt] = *(const short8*)&w6[(nt + 4) * 4096 + z1];
#pragma unroll
        for (int nt = 0; nt < 8; ++nt)
            asm volatile("v_mfma_f32_16x16x32_bf16 %0, %1, %2, %0"
                         : "+v"(acc[nt]) : "v"(a1), "a"(wa[nt][1]));
        // kf2 + issue w7a
        short8 a2 = *(const short8*)&hcur[2 * 512 + swl];
        int z2 = gated_zero_f(cst[0]);
        short8 w7a[4];
#pragma unroll
        for (int nt = 0; nt < 4; ++nt) w7a[nt] = *(const short8*)&w6[nt * 4096 + 512 + z2];
#pragma unroll
        for (int nt = 0; nt < 8; ++nt)
            asm volatile("v_mfma_f32_16x16x32_bf16 %0, %1, %2, %0"
                         : "+v"(acc[nt]) : "v"(a2), "a"(wa[nt][2]));
        // consume kf6 first half (builtin)
        short8 a6 = *(const short8*)&hcur[6 * 512 + swl];
#pragma unroll
        for (int nt = 0; nt < 4; ++nt)
            acc[nt] = __builtin_amdgcn_mfma_f32_16x16x32_bf16(a6, w6a[nt], acc[nt], 0, 0, 0);
        // kf3 + issue w7b
        short8 a3 = *(const short8*)&hcur[3 * 512 + swl];
        int z3 = gated_zero_f(cst[0]);
        short8 w7b[4];
#pragma unroll
        for (int nt = 0; nt < 4; ++nt) w7b[nt] = *(const short8*)&w6[(nt + 4) * 4096 + 512 + z3];
#pragma unroll
        for (int nt = 0; nt < 8; ++nt)
            asm volatile("v_mfma_f32_16x16x32_bf16 %0, %1, %2, %0"
                         : "+v"(acc[nt]) : "v"(a3), "a"(wa[nt][3]));
        // xg prefetch for next step — after all stream loads (in-order vmcnt)
        uint4 xn0 = ((const uint4*)xp)[0];
        uint4 xn1 = ((const uint4*)xp)[1];
        uint4 xn2 = ((const uint4*)xp)[2];
        uint4 xn3 = ((const uint4*)xp)[3];
        // consume kf6 second half (builtin)
#pragma unroll
        for (int nt = 4; nt < 8; ++nt)
            acc[nt] = __builtin_amdgcn_mfma_f32_16x16x32_bf16(a6, w6b[nt - 4], acc[nt], 0, 0, 0);
        // kf5 (LDS, builtin)
        {
            short8 a5 = *(const short8*)&hcur[5 * 512 + swl];
#pragma unroll
            for (int nt = 0; nt < 8; ++nt) {
                short8 b = *(const short8*)&wl[((wv * 8 + nt) * 2 + 1) * 512 + lane * 8];
                acc[nt] = __builtin_amdgcn_mfma_f32_16x16x32_bf16(a5, b, acc[nt], 0, 0, 0);
            }
        }
        // kf7 (streamed, builtin — last writer)
        short8 a7 = *(const short8*)&hcur[7 * 512 + swl];
#pragma unroll
        for (int nt = 0; nt < 4; ++nt)
            acc[nt] = __builtin_amdgcn_mfma_f32_16x16x32_bf16(a7, w7a[nt], acc[nt], 0, 0, 0);
#pragma unroll
        for (int nt = 4; nt < 8; ++nt)
            acc[nt] = __builtin_amdgcn_mfma_f32_16x16x32_bf16(a7, w7b[nt - 4], acc[nt], 0, 0, 0);

        // epilogue: gates -> c,h (rcp-based activations)
        float hv[8];
#pragma unroll
        for (int hh = 0; hh < 2; ++hh)
#pragma unroll
            for (int r = 0; r < 4; ++r) {
                float ig = sigm(acc[0 + hh][r]);
                float fg = sigm(acc[2 + hh][r]);
                float gg = tanh_f(acc[4 + hh][r]);
                float og = sigm(acc[6 + hh][r]);
                float c = fg * cst[hh * 4 + r] + ig * gg;
                cst[hh * 4 + r] = c;
                hv[hh * 4 + r] = og * tanh_f(c);
            }
        uint32 p01, p23, p45, p67;
        asm volatile("v_cvt_pk_bf16_f32 %0, %1, %2" : "=v"(p01) : "v"(hv[0]), "v"(hv[1]));
        asm volatile("v_cvt_pk_bf16_f32 %0, %1, %2" : "=v"(p23) : "v"(hv[2]), "v"(hv[3]));
        asm volatile("v_cvt_pk_bf16_f32 %0, %1, %2" : "=v"(p45) : "v"(hv[4]), "v"(hv[5]));
        asm volatile("v_cvt_pk_bf16_f32 %0, %1, %2" : "=v"(p67) : "v"(hv[6]), "v"(hv[7]));
        ushort16 hb[8];
        hb[0] = (ushort16)p01; hb[1] = (ushort16)(p01 >> 16);
        hb[2] = (ushort16)p23; hb[3] = (ushort16)(p23 >> 16);
        hb[4] = (ushort16)p45; hb[5] = (ushort16)(p45 >> 16);
        hb[6] = (ushort16)p67; hb[7] = (ushort16)(p67 >> 16);

        ushort16* hnxt = hf + (cur ^ 1) * 4096;
#pragma unroll
        for (int hh = 0; hh < 2; ++hh)
#pragma unroll
            for (int r = 0; r < 4; ++r) {
                hnxt[dsa[hh * 4 + r]] = hb[hh * 4 + r];
                if (valid) hp[r * 512 + hh * 16] = hb[hh * 4 + r];   // fire-and-forget
            }
        hp += hstep;

        // raw barrier: wait ONLY LDS ops (h dbuf exchange); vmcnt stays outstanding
        __builtin_amdgcn_sched_barrier(0);
        asm volatile("s_waitcnt lgkmcnt(0)" ::: "memory");
        __builtin_amdgcn_s_barrier();
        __builtin_amdgcn_sched_barrier(0);

        xc0 = xn0; xc1 = xn1; xc2 = xn2; xc3 = xn3;
        cur ^= 1;
    }
}

// ---------------- logits = h1[t*64+b][512](bf16) @ clsW[9,512]^T + clsb -> f32 [b][t][9] ----------------
__global__ __launch_bounds__(256) void k_logits(const ushort16* __restrict__ h1,
                                                const float* __restrict__ Wc,
                                                const float* __restrict__ bc,
                                                float* __restrict__ out) {
    __shared__ ushort16 hs[16 * 512];
    __shared__ float wsm[9 * 512];
    __shared__ float bs[9];
    const int tid = threadIdx.x;
    const size_t row0 = (size_t)blockIdx.x * 16;
    const uint4* src = (const uint4*)(h1 + row0 * 512);
    uint4* dst = (uint4*)hs;
#pragma unroll
    for (int i = 0; i < 4; i++) dst[tid + i * 256] = src[tid + i * 256];
    for (int i = tid; i < 4608; i += 256) wsm[i] = Wc[i];
    if (tid < 9) bs[tid] = bc[tid];
    __syncthreads();
    if (tid < 144) {
        int r = tid / 9, l = tid - r * 9;
        float acc = bs[l];
        const ushort16* hr = &hs[r * 512];
        const float* wrow = &wsm[l * 512];
        for (int k = 0; k < 512; k++) acc += bf2f(hr[k]) * wrow[k];
        int rowidx = (int)row0 + r;             // t-major: row = t*64 + b
        int bb = rowidx & 63, tt = rowidx >> 6;
        out[((size_t)bb * 512 + tt) * 9 + l] = acc;
    }
}

// ---------------- CRF NLL per batch (timesteps [1, 511)) ----------------
__global__ __launch_bounds__(64) void k_crf(const float* __restrict__ logits,
                                            const int* __restrict__ labels,
                                            const float* __restrict__ start,
                                            const float* __restrict__ endv,
                                            const float* __restrict__ trans,
                                            float* __restrict__ perb) {
    const int b = blockIdx.x, lane = threadIdx.x;
    __shared__ float tr[81];
    __shared__ float emb[510 * 9];
    for (int i = lane; i < 81; i += 64) tr[i] = trans[i];
    const float* em = logits + (size_t)b * 512 * 9;
    for (int i = lane; i < 4590; i += 64) emb[i] = em[9 + i];
    __syncthreads();
    const int* lb = labels + (size_t)b * 512;

    float acc = 0.f;
    for (int s = lane; s < 510; s += 64) acc += emb[s * 9 + lb[s + 1]];
    for (int s = lane; s < 509; s += 64) acc += tr[lb[s + 1] * 9 + lb[s + 2]];
#pragma unroll
    for (int off = 32; off; off >>= 1) acc += __shfl_down(acc, off);

    const int j = (lane < 9) ? lane : 0;
    float alpha = start[j] + emb[j];
    for (int s = 1; s < 510; ++s) {
        float v[9];
        float m = -3.4e38f;
#pragma unroll
        for (int i = 0; i < 9; i++) {
            float ai = __shfl(alpha, i);
            float t = ai + tr[i * 9 + j];
            v[i] = t;
            m = fmaxf(m, t);
        }
        float sum = 0.f;
#pragma unroll
        for (int i = 0; i < 9; i++) sum += __expf(v[i] - m);
        alpha = m + __logf(sum) + emb[s * 9 + j];
    }
    float ae = alpha + endv[j];
    float mm = -3.4e38f;
#pragma unroll
    for (int i = 0; i < 9; i++) mm = fmaxf(mm, __shfl(ae, i));
    float ss = 0.f;
#pragma unroll
    for (int i = 0; i < 9; i++) ss += __expf(__shfl(ae, i) - mm);
    float logZ = mm + __logf(ss);
    if (lane == 0) {
        float num = acc + start[lb[1]] + endv[lb[510]];
        perb[b] = logZ - num;
    }
}

__global__ __launch_bounds__(64) void k_reduce(const float* __restrict__ perb,
                                               float* __restrict__ out) {
    float v = perb[threadIdx.x];
#pragma unroll
    for (int off = 32; off; off >>= 1) v += __shfl_down(v, off);
    if (threadIdx.x == 0) out[0] = v * (1.f / 64.f);
}

extern "C" void kernel_launch(void* const* d_in, const int* in_sizes, int n_in,
                              void* d_out, int out_size, void* d_ws, size_t ws_size,
                              hipStream_t stream) {
    const float* features = (const float*)d_in[0];
    const int*   labels   = (const int*)d_in[1];
    const float* w0ih = (const float*)d_in[3];
    const float* w0hh = (const float*)d_in[4];
    const float* b0   = (const float*)d_in[5];
    const float* w1ih = (const float*)d_in[6];
    const float* w1hh = (const float*)d_in[7];
    const float* b1   = (const float*)d_in[8];
    const float* clsW = (const float*)d_in[9];
    const float* clsb = (const float*)d_in[10];
    const float* cstart = (const float*)d_in[11];
    const float* cend   = (const float*)d_in[12];
    const float* ctrans = (const float*)d_in[13];

    char* ws = (char*)d_ws;
    ushort16* featbf = (ushort16*)(ws + 0);              // t-major [t*64+b][768]
    ushort16* h1buf  = (ushort16*)(ws + 0);              // reuses feat region after GEMM0
    ushort16* xg2    = (ushort16*)(ws + 50331648);       // 134217728 B
    ushort16* h0     = (ushort16*)(ws + 184549376);      // 33554432 B (t-major)
    ushort16* wih0   = (ushort16*)(ws + 218103808);
    ushort16* wih1   = (ushort16*)(ws + 221249536);
    ushort16* w2_0   = (ushort16*)(ws + 223346688);
    ushort16* w2_1   = (ushort16*)(ws + 224395264);
    float*    perb   = (float*)(ws + 225443840);

    float* outF = (float*)d_out;
    float* logitsF = outF + 1;

    k_cvt_tmaj<<<dim3(2048), dim3(256), 0, stream>>>(features, featbf, 25165824 / 4);
    k_cvt_bf16<<<dim3(512), dim3(256), 0, stream>>>(w0ih, wih0, 1572864 / 4);
    k_cvt_bf16<<<dim3(512), dim3(256), 0, stream>>>(w1ih, wih1, 1048576 / 4);
    k_wfrag<<<dim3(2048), dim3(256), 0, stream>>>(w0hh, w2_0);
    k_wfrag<<<dim3(2048), dim3(256), 0, stream>>>(w1hh, w2_1);

    // layer 0 (A rows t-major for both GEMMs)
    k_gemm_xg<<<dim3(256, 16), dim3(256), 0, stream>>>(featbf, wih0, b0, xg2, 32768, 2048, 768);
    k_lstm_scan5<<<dim3(16), dim3(512), 147456, stream>>>(xg2, w2_0, h0);
    // layer 1
    k_gemm_xg<<<dim3(256, 16), dim3(256), 0, stream>>>(h0, wih1, b1, xg2, 32768, 2048, 512);
    k_lstm_scan5<<<dim3(16), dim3(512), 147456, stream>>>(xg2, w2_1, h1buf);
    // classifier + CRF
    k_logits<<<dim3(2048), dim3(256), 0, stream>>>(h1buf, clsW, clsb, logitsF);
    k_crf<<<dim3(64), dim3(64), 0, stream>>>(logitsF, labels, cstart, cend, ctrans, perb);
    k_reduce<<<dim3(1), dim3(64), 0, stream>>>(perb, outF);
}